// Round 6
// baseline (1089.484 us; speedup 1.0000x reference)
//
#include <hip/hip_runtime.h>
#include <hip/hip_bf16.h>

#define N_HEAD 8
#define D_MODEL 512
#define D_HEAD 64
#define D_HIDDEN 2048
#define NTOK 64
#define BATCH 4096

typedef __attribute__((ext_vector_type(4))) float f32x4;
typedef __attribute__((ext_vector_type(8))) short short8;
typedef __attribute__((ext_vector_type(8))) unsigned short u16x8;

__device__ __forceinline__ float bf2f(unsigned short u) {
    return __uint_as_float(((unsigned int)u) << 16);
}
__device__ __forceinline__ unsigned short f2bf(float f) {
    unsigned int b = __float_as_uint(f);
    b += 0x7fffu + ((b >> 16) & 1u);
    return (unsigned short)(b >> 16);
}
__device__ __forceinline__ float wave_sum(float v) {
    v += __shfl_xor(v, 32); v += __shfl_xor(v, 16); v += __shfl_xor(v, 8);
    v += __shfl_xor(v, 4);  v += __shfl_xor(v, 2);  v += __shfl_xor(v, 1);
    return v;
}
__device__ __forceinline__ void gload_lds16(const void* g, void* l) {
    __builtin_amdgcn_global_load_lds(
        (const __attribute__((address_space(1))) unsigned int*)g,
        (__attribute__((address_space(3))) unsigned int*)l, 16, 0, 0);
}

// ---------------------------------------------------------------------------
// K0: merged prep. y=0..2: transpose {Wv,W1,W2} f32 -> bf16 (N x K);
// y=3: u[c][h] bf16 (512 x 8), u[c][h] = sum_d Wk[c][h*64+d]*score_w[h][d]
// (per-head consts cancel in softmax over n, so bk/score_b are unused).
// ---------------------------------------------------------------------------
__global__ __launch_bounds__(256) void prep_all(
    const float* __restrict__ Wk, const float* __restrict__ score_w,
    const float* __restrict__ Wv, const float* __restrict__ W1,
    const float* __restrict__ W2,
    unsigned short* __restrict__ u,
    unsigned short* __restrict__ WvT, unsigned short* __restrict__ W1T,
    unsigned short* __restrict__ W2T) {
    int m = blockIdx.y;
    if (m == 3) {
        int idx = blockIdx.x * 256 + threadIdx.x;
        if (blockIdx.x < 16) {
            int c = idx >> 3, h = idx & 7;
            float s = 0.f;
            #pragma unroll 8
            for (int d = 0; d < D_HEAD; ++d)
                s += Wk[c * D_MODEL + h * D_HEAD + d] * score_w[h * D_HEAD + d];
            u[c * 8 + h] = f2bf(s);
        }
        return;
    }
    const float* in; unsigned short* out; int K, N, tX, tiles;
    if (m == 0)      { in = Wv; out = WvT; K = 512;  N = 512;  tX = 16; tiles = 256;  }
    else if (m == 1) { in = W1; out = W1T; K = 512;  N = 2048; tX = 64; tiles = 1024; }
    else             { in = W2; out = W2T; K = 2048; N = 512;  tX = 16; tiles = 1024; }
    int t = blockIdx.x;
    if (t >= tiles) return;
    int n0 = (t % tX) * 32, k0 = (t / tX) * 32;
    __shared__ float tile[32][33];
    int tx = threadIdx.x & 31, ty = threadIdx.x >> 5;
    #pragma unroll
    for (int i = ty; i < 32; i += 8)
        tile[i][tx] = in[(size_t)(k0 + i) * N + n0 + tx];
    __syncthreads();
    #pragma unroll
    for (int i = ty; i < 32; i += 8)
        out[(size_t)(n0 + i) * K + k0 + tx] = f2bf(tile[tx][i]);
}

// ---------------------------------------------------------------------------
// K1 v6: score+softmax+pool entirely in registers (no LDS x-tile).
// Wave owns 16 tokens, lane owns 8 channels.  Scores: per-lane partial + 6
// in-wave shfl_xor (all lanes end with the full s[n][h]).  Pool numerator
// acc[h][cc] += exp(s)*x accumulates in regs against the just-loaded values.
// x read ONCE from HBM, ping-pong reg prefetch (passes of 4 tokens).
// Only cross-wave pool-reduce touches LDS (stride-65 f32, conflict-free) with
// raw s_barrier + lgkmcnt-only waits (prefetch loads stay in flight).
// 2048 blocks x 2 batches, 256 threads, ~50 KB LDS, 2 blocks/CU.
// ---------------------------------------------------------------------------
__global__ __launch_bounds__(256, 2) void score_pool_v6(
    const float* __restrict__ x, const unsigned short* __restrict__ u,
    unsigned short* __restrict__ pooled) {
    __shared__ float red[3][64][65];   // 49.9 KB cross-wave partials
    __shared__ float zl[4][8];

    const int tid = threadIdx.x;
    const int l = tid & 63, w = tid >> 6;

    // lane's u slice: channels c = l*8+cc, 8 heads each, bf16-packed (16 VGPR)
    u16x8 upkc[8];
    #pragma unroll
    for (int cc = 0; cc < 8; ++cc)
        upkc[cc] = *(const u16x8*)(u + (size_t)(l * 8 + cc) * 8);

    const int b0 = blockIdx.x * 2;

    f32x4 preA[8], preB[8];

#define LOADP(dst, base, p)                                                   \
    {                                                                         \
        _Pragma("unroll") for (int r = 0; r < 4; ++r) {                       \
            const float* ptr = (base) + (w * 16 + (p) * 4 + r) * D_MODEL + l * 8; \
            dst[r * 2]     = *(const f32x4*)ptr;                              \
            dst[r * 2 + 1] = *(const f32x4*)(ptr + 4);                        \
        }                                                                     \
    }

    float acc[64];
    float zacc[8];

    auto process = [&](const f32x4 (&cur)[8]) {
        float pr[4][8];
        #pragma unroll
        for (int r = 0; r < 4; ++r)
            #pragma unroll
            for (int h = 0; h < 8; ++h) pr[r][h] = 0.f;
        #pragma unroll
        for (int cc = 0; cc < 8; ++cc) {
            float uh[8];
            #pragma unroll
            for (int h = 0; h < 8; ++h) uh[h] = bf2f(upkc[cc][h]);
            #pragma unroll
            for (int r = 0; r < 4; ++r) {
                float xv = (cc < 4) ? cur[r * 2][cc] : cur[r * 2 + 1][cc - 4];
                #pragma unroll
                for (int h = 0; h < 8; ++h) pr[r][h] += xv * uh[h];
            }
        }
        // in-wave butterfly: every lane ends with full s[n][h]
        #pragma unroll
        for (int r = 0; r < 4; ++r) {
            #pragma unroll
            for (int h = 0; h < 8; ++h) {
                float v = pr[r][h];
                v += __shfl_xor(v, 1);  v += __shfl_xor(v, 2);
                v += __shfl_xor(v, 4);  v += __shfl_xor(v, 8);
                v += __shfl_xor(v, 16); v += __shfl_xor(v, 32);
                pr[r][h] = v;
            }
        }
        // exp (scores are O(0.1): no max subtraction) + pool accumulate
        #pragma unroll
        for (int r = 0; r < 4; ++r) {
            float e[8];
            #pragma unroll
            for (int h = 0; h < 8; ++h) {
                e[h] = __expf(pr[r][h]);
                zacc[h] += e[h];
            }
            #pragma unroll
            for (int cc = 0; cc < 8; ++cc) {
                float xv = (cc < 4) ? cur[r * 2][cc] : cur[r * 2 + 1][cc - 4];
                #pragma unroll
                for (int h = 0; h < 8; ++h) acc[h * 8 + cc] += e[h] * xv;
            }
        }
    };

    // prologue: pass 0 of batch b0
    {
        const float* xb = x + (size_t)b0 * (NTOK * D_MODEL);
        LOADP(preA, xb, 0);
    }

    #pragma unroll 1
    for (int i = 0; i < 2; ++i) {
        const float* xb  = x + (size_t)(b0 + i) * (NTOK * D_MODEL);
        const float* xbn = x + (size_t)(b0 + i + 1) * (NTOK * D_MODEL);
        #pragma unroll
        for (int j = 0; j < 64; ++j) acc[j] = 0.f;
        #pragma unroll
        for (int h = 0; h < 8; ++h) zacc[h] = 0.f;

        LOADP(preB, xb, 1);
        process(preA);
        LOADP(preA, xb, 2);
        process(preB);
        LOADP(preB, xb, 3);
        process(preA);
        if (i == 0) LOADP(preA, xbn, 0);   // next batch pass 0, in flight across reduce
        process(preB);

        // ---- cross-wave pool reduce (waves 1-3 write, wave 0 sums) ----
        if (w) {
            #pragma unroll
            for (int j = 0; j < 64; ++j) red[w - 1][l][j] = acc[j];
        }
        if (l < 8) zl[w][l] = zacc[l];
        asm volatile("s_waitcnt lgkmcnt(0)" ::: "memory");
        __builtin_amdgcn_s_barrier();
        if (w == 0) {
            #pragma unroll
            for (int j = 0; j < 64; ++j)
                acc[j] += red[0][l][j] + red[1][l][j] + red[2][l][j];
            float rz[8];
            #pragma unroll
            for (int h = 0; h < 8; ++h)
                rz[h] = 1.f / (zl[0][h] + zl[1][h] + zl[2][h] + zl[3][h]);
            unsigned short* pb = pooled + (size_t)(b0 + i) * (N_HEAD * D_MODEL);
            #pragma unroll
            for (int h = 0; h < 8; ++h) {
                u16x8 o;
                #pragma unroll
                for (int cc = 0; cc < 8; ++cc) o[cc] = f2bf(acc[h * 8 + cc] * rz[h]);
                *(u16x8*)(pb + h * D_MODEL + l * 8) = o;
            }
        }
        asm volatile("s_waitcnt lgkmcnt(0)" ::: "memory");
        __builtin_amdgcn_s_barrier();   // red/zl safe to reuse next batch
    }
#undef LOADP
}

// ---------------------------------------------------------------------------
// MFMA GEMM (unchanged): global_load_lds staging, XOR-swizzled via
// pre-swizzled global source, 4 waves (2x2).  MODE 0: per-head, bf16+bias.
// MODE 1: bf16, gelu(+bias).  MODE 2: f32, +bias +residual(bf16).
// ---------------------------------------------------------------------------
template <int BM, int BN, int MODE>
__global__ __launch_bounds__(256) void gemm_mf(
    const unsigned short* __restrict__ A, int lda,
    const unsigned short* __restrict__ BT,
    const float* __restrict__ bias,
    void* __restrict__ Cout, int ldc,
    const unsigned short* __restrict__ res, int K) {
    __shared__ unsigned short Al[BM * 64];
    __shared__ unsigned short Bl[BN * 64];
    int m0 = blockIdx.x * BM;
    int n0;
    const unsigned short* Ap = A;
    const unsigned short* Bp;
    const float* bp;
    if (MODE == 0) {
        int h = blockIdx.y;
        Ap = A + (size_t)h * 512;
        Bp = BT + (size_t)h * 64 * K;
        bp = bias + h * 64;
        n0 = h * 64;
    } else {
        n0 = blockIdx.y * BN;
        Bp = BT + (size_t)n0 * K;
        bp = bias + n0;
    }
    int tid = threadIdx.x, l = tid & 63, w = tid >> 6;
    int lr = l & 15, lq = l >> 4;
    int wm = w >> 1, wn = w & 1;
    constexpr int MR = BM / 32, NR = BN / 32;
    constexpr int AI = BM / 8, BI = BN / 8;

    f32x4 acc[MR][NR];
    #pragma unroll
    for (int mi = 0; mi < MR; ++mi)
        #pragma unroll
        for (int nj = 0; nj < NR; ++nj) acc[mi][nj] = (f32x4){0.f, 0.f, 0.f, 0.f};

    int srow = l >> 3;
    int scol = ((l & 7) ^ ((l >> 3) & 7)) << 3;

    for (int k0 = 0; k0 < K; k0 += 64) {
        #pragma unroll
        for (int j = 0; j < AI / 4; ++j) {
            int ji = w * (AI / 4) + j;
            const unsigned short* src = Ap + (size_t)(m0 + ji * 8 + srow) * lda + k0 + scol;
            gload_lds16(src, &Al[ji * 512]);
        }
        #pragma unroll
        for (int j = 0; j < BI / 4; ++j) {
            int ji = w * (BI / 4) + j;
            const unsigned short* src = Bp + (size_t)(ji * 8 + srow) * K + k0 + scol;
            gload_lds16(src, &Bl[ji * 512]);
        }
        __syncthreads();
        #pragma unroll
        for (int kk = 0; kk < 64; kk += 32) {
            int sw = (kk + lq * 8) ^ ((l & 7) << 3);
            short8 af[MR], bf[NR];
            #pragma unroll
            for (int mi = 0; mi < MR; ++mi)
                af[mi] = *(const short8*)&Al[(wm * (BM / 2) + mi * 16 + lr) * 64 + sw];
            #pragma unroll
            for (int nj = 0; nj < NR; ++nj)
                bf[nj] = *(const short8*)&Bl[(wn * (BN / 2) + nj * 16 + lr) * 64 + sw];
            #pragma unroll
            for (int mi = 0; mi < MR; ++mi)
                #pragma unroll
                for (int nj = 0; nj < NR; ++nj)
                    acc[mi][nj] = __builtin_amdgcn_mfma_f32_16x16x32_bf16(
                        af[mi], bf[nj], acc[mi][nj], 0, 0, 0);
        }
        __syncthreads();
    }

    #pragma unroll
    for (int mi = 0; mi < MR; ++mi) {
        #pragma unroll
        for (int nj = 0; nj < NR; ++nj) {
            #pragma unroll
            for (int j = 0; j < 4; ++j) {
                int row = m0 + wm * (BM / 2) + mi * 16 + lq * 4 + j;
                int nl = wn * (BN / 2) + nj * 16 + lr;
                int col = n0 + nl;
                float v = acc[mi][nj][j] + bp[nl];
                if (MODE == 1) {
                    v = 0.5f * v * (1.0f + erff(v * 0.70710678118654752f));
                }
                if (MODE == 2) {
                    v += bf2f(res[(size_t)row * 512 + col]);
                    ((float*)Cout)[(size_t)row * ldc + col] = v;
                } else {
                    ((unsigned short*)Cout)[(size_t)row * ldc + col] = f2bf(v);
                }
            }
        }
    }
}

// ---------------------------------------------------------------------------
// K5: in-place LayerNorm over 512, one wave per row
// ---------------------------------------------------------------------------
__global__ __launch_bounds__(256) void ln_kernel(
    float* __restrict__ y, const float* __restrict__ g, const float* __restrict__ bta) {
    int row = blockIdx.x * 4 + (threadIdx.x >> 6);
    int l = threadIdx.x & 63;
    float* yp = y + (size_t)row * D_MODEL;
    float4 v0 = *(const float4*)(yp + l * 8);
    float4 v1 = *(const float4*)(yp + l * 8 + 4);
    float vv[8] = {v0.x, v0.y, v0.z, v0.w, v1.x, v1.y, v1.z, v1.w};
    float s = 0.f;
    #pragma unroll
    for (int i = 0; i < 8; ++i) s += vv[i];
    s = wave_sum(s);
    float mean = s * (1.f / 512.f);
    float q = 0.f;
    #pragma unroll
    for (int i = 0; i < 8; ++i) { float d = vv[i] - mean; q += d * d; }
    q = wave_sum(q);
    float rstd = rsqrtf(q * (1.f / 512.f) + 1e-5f);
    float4 g0 = *(const float4*)(g + l * 8);
    float4 g1 = *(const float4*)(g + l * 8 + 4);
    float4 b0 = *(const float4*)(bta + l * 8);
    float4 b1 = *(const float4*)(bta + l * 8 + 4);
    float gv[8] = {g0.x, g0.y, g0.z, g0.w, g1.x, g1.y, g1.z, g1.w};
    float bv[8] = {b0.x, b0.y, b0.z, b0.w, b1.x, b1.y, b1.z, b1.w};
    float ov[8];
    #pragma unroll
    for (int i = 0; i < 8; ++i) ov[i] = (vv[i] - mean) * rstd * gv[i] + bv[i];
    float4 o0 = {ov[0], ov[1], ov[2], ov[3]};
    float4 o1 = {ov[4], ov[5], ov[6], ov[7]};
    *(float4*)(yp + l * 8) = o0;
    *(float4*)(yp + l * 8 + 4) = o1;
}

extern "C" void kernel_launch(void* const* d_in, const int* in_sizes, int n_in,
                              void* d_out, int out_size, void* d_ws, size_t ws_size,
                              hipStream_t stream) {
    const float* x       = (const float*)d_in[0];
    const float* Wk      = (const float*)d_in[1];
    const float* Wv      = (const float*)d_in[3];
    const float* bv      = (const float*)d_in[4];
    const float* score_w = (const float*)d_in[5];
    const float* W1      = (const float*)d_in[7];
    const float* b1      = (const float*)d_in[8];
    const float* W2      = (const float*)d_in[9];
    const float* b2      = (const float*)d_in[10];
    const float* ln_g    = (const float*)d_in[11];
    const float* ln_b    = (const float*)d_in[12];
    float* out = (float*)d_out;

    char* ws = (char*)d_ws;
    size_t off = 0;
    auto alloc = [&](size_t sz) {
        void* p = ws + off;
        off = (off + sz + 1023) & ~(size_t)1023;
        return p;
    };
    unsigned short* u   = (unsigned short*)alloc((size_t)D_MODEL * N_HEAD * 2);
    unsigned short* WvT = (unsigned short*)alloc((size_t)512 * 512 * 2);
    unsigned short* W1T = (unsigned short*)alloc((size_t)2048 * 512 * 2);
    unsigned short* W2T = (unsigned short*)alloc((size_t)512 * 2048 * 2);
    unsigned short* pooled = (unsigned short*)alloc((size_t)BATCH * N_HEAD * D_MODEL * 2);
    unsigned short* feat   = (unsigned short*)alloc((size_t)BATCH * D_MODEL * 2);
    unsigned short* Hbuf   = (unsigned short*)alloc((size_t)BATCH * D_HIDDEN * 2);

    prep_all<<<dim3(1024, 4), dim3(256), 0, stream>>>(
        Wk, score_w, Wv, W1, W2, u, WvT, W1T, W2T);
    score_pool_v6<<<dim3(2048), dim3(256), 0, stream>>>(x, u, pooled);
    // proj: feature = pooled @ blockdiag(Wv per head) + bv
    gemm_mf<128, 64, 0><<<dim3(32, 8), dim3(256), 0, stream>>>(
        pooled, N_HEAD * D_MODEL, WvT, bv, (void*)feat, D_MODEL,
        (const unsigned short*)nullptr, 512);
    // ffn1: H = gelu(feature @ W1 + b1)
    gemm_mf<128, 128, 1><<<dim3(32, 16), dim3(256), 0, stream>>>(
        feat, D_MODEL, W1T, b1, (void*)Hbuf, D_HIDDEN,
        (const unsigned short*)nullptr, 512);
    // ffn2: y = H @ W2 + b2 + feature  (f32 -> d_out)
    gemm_mf<64, 128, 2><<<dim3(64, 4), dim3(256), 0, stream>>>(
        Hbuf, D_HIDDEN, W2T, b2, (void*)out, D_MODEL, feat, 2048);
    ln_kernel<<<dim3(1024), dim3(256), 0, stream>>>(out, ln_g, ln_b);
}

// Round 8
// 292.516 us; speedup vs baseline: 3.7245x; 3.7245x over previous
//
#include <hip/hip_runtime.h>
#include <hip/hip_bf16.h>

#define N_HEAD 8
#define D_MODEL 512
#define D_HEAD 64
#define D_HIDDEN 2048
#define NTOK 64
#define BATCH 4096

typedef __attribute__((ext_vector_type(4))) float f32x4;
typedef __attribute__((ext_vector_type(8))) short short8;
typedef __attribute__((ext_vector_type(8))) unsigned short u16x8;

__device__ __forceinline__ float bf2f(unsigned short u) {
    return __uint_as_float(((unsigned int)u) << 16);
}
__device__ __forceinline__ unsigned short f2bf(float f) {
    unsigned int b = __float_as_uint(f);
    b += 0x7fffu + ((b >> 16) & 1u);
    return (unsigned short)(b >> 16);
}
__device__ __forceinline__ float wave_sum(float v) {
    v += __shfl_xor(v, 32); v += __shfl_xor(v, 16); v += __shfl_xor(v, 8);
    v += __shfl_xor(v, 4);  v += __shfl_xor(v, 2);  v += __shfl_xor(v, 1);
    return v;
}
__device__ __forceinline__ void gload_lds16(const void* g, void* l) {
    __builtin_amdgcn_global_load_lds(
        (const __attribute__((address_space(1))) unsigned int*)g,
        (__attribute__((address_space(3))) unsigned int*)l, 16, 0, 0);
}

// ---------------------------------------------------------------------------
// K0: merged prep. y=0..2: transpose {Wv,W1,W2} f32 -> bf16 (N x K);
// y=3: uT[16][512] bf16, uT[h][c] = sum_d Wk[c][h*64+d]*score_w[h][d],
// heads 8..15 zero (per-head consts cancel in softmax; bk/score_b unused).
// ---------------------------------------------------------------------------
__global__ __launch_bounds__(256) void prep_all(
    const float* __restrict__ Wk, const float* __restrict__ score_w,
    const float* __restrict__ Wv, const float* __restrict__ W1,
    const float* __restrict__ W2,
    unsigned short* __restrict__ uT,
    unsigned short* __restrict__ WvT, unsigned short* __restrict__ W1T,
    unsigned short* __restrict__ W2T) {
    int m = blockIdx.y;
    if (m == 3) {
        int idx = blockIdx.x * 256 + threadIdx.x;
        if (idx < 16 * 512) {
            int h = idx & 15, c = idx >> 4;
            float s = 0.f;
            if (h < 8) {
                #pragma unroll 8
                for (int d = 0; d < D_HEAD; ++d)
                    s += Wk[c * D_MODEL + h * D_HEAD + d] * score_w[h * D_HEAD + d];
            }
            uT[h * D_MODEL + c] = f2bf(s);
        }
        return;
    }
    const float* in; unsigned short* out; int K, N, tX, tiles;
    if (m == 0)      { in = Wv; out = WvT; K = 512;  N = 512;  tX = 16; tiles = 256;  }
    else if (m == 1) { in = W1; out = W1T; K = 512;  N = 2048; tX = 64; tiles = 1024; }
    else             { in = W2; out = W2T; K = 2048; N = 512;  tX = 16; tiles = 1024; }
    int t = blockIdx.x;
    if (t >= tiles) return;
    int n0 = (t % tX) * 32, k0 = (t / tX) * 32;
    __shared__ float tile[32][33];
    int tx = threadIdx.x & 31, ty = threadIdx.x >> 5;
    #pragma unroll
    for (int i = ty; i < 32; i += 8)
        tile[i][tx] = in[(size_t)(k0 + i) * N + n0 + tx];
    __syncthreads();
    #pragma unroll
    for (int i = ty; i < 32; i += 8)
        out[(size_t)(n0 + i) * K + k0 + tx] = f2bf(tile[tx][i]);
}

// ---------------------------------------------------------------------------
// K1 v7b: v7 with the cross-half reduce slot aliasing fixed (stride-20 linear
// slots, no XOR — the v7 XOR escaped its 16-float slot and collided with the
// neighbor slot's writes).  512 blocks (2/CU via 76 KB LDS), 512 threads,
// 8 batches/block.  Phases A (MFMA scores) and B (softmax) identical to
// validated v5.  Phase C: thread = 8ch x 2heads x 32tok, one b128 x-read +
// one b64 attn broadcast per token; 2-way cross-half reduce through 20 KB
// scratch reusing the xl region (barrier-ordered).  x read ONCE from HBM;
// prefetch regs stay in flight across raw s_barriers (lgkmcnt-only waits).
// ---------------------------------------------------------------------------
__global__ __launch_bounds__(512, 4) void score_pool_v7(
    const float* __restrict__ x, const unsigned short* __restrict__ uT,
    unsigned short* __restrict__ pooled) {
    __shared__ unsigned short xl[NTOK * D_MODEL];   // 64 KB (also reduce scratch)
    __shared__ unsigned short ul[8 * D_MODEL];      // 8 KB swizzled uT rows 0..7
    __shared__ float attn_l[NTOK * 8];              // 2 KB  [n][h] f32
    __shared__ float zred[4][16];                   // 256 B

    const int tid = threadIdx.x;
    const int l = tid & 63, w = tid >> 6;
    const int hg = l >> 4;          // 0..3 : k-subgroup / head group (phase A)
    const int lr = l & 15;          // row/col-in-tile lane id

    // copy u^T rows 0..7 into LDS (swizzled like xl rows)
    {
        int r = tid >> 6;            // 0..7
        int c8 = (tid & 63) * 8;
        u16x8 v = *(const u16x8*)(uT + r * D_MODEL + c8);
        *(u16x8*)&ul[r * D_MODEL + (c8 ^ (r << 3))] = v;
    }

    const int b0 = blockIdx.x * 8;

    // staging geometry: thread owns 8 consecutive channels x 8 tokens
    const int sc8 = (tid & 63) * 8;       // channel octet base
    const int st0 = tid >> 6;             // tokens st0 + 8j
    const int sswz = (st0 & 7) << 3;      // constant per thread (8j doesn't change &7)

    // prologue: prefetch batch b0 (64 floats / thread)
    float4 pre[16];
    {
        const float* xb = x + (size_t)b0 * (NTOK * D_MODEL);
        #pragma unroll
        for (int j = 0; j < 8; ++j) {
            const float* p = xb + (st0 + 8 * j) * D_MODEL + sc8;
            pre[2 * j]     = *(const float4*)p;
            pre[2 * j + 1] = *(const float4*)(p + 4);
        }
    }

    #pragma unroll 1
    for (int i = 0; i < 8; ++i) {
        // ---- stage: regs -> swizzled bf16 LDS (8 x b128 writes) ----
        #pragma unroll
        for (int j = 0; j < 8; ++j) {
            float4 a = pre[2 * j], b = pre[2 * j + 1];
            u16x8 o;
            o[0] = f2bf(a.x); o[1] = f2bf(a.y); o[2] = f2bf(a.z); o[3] = f2bf(a.w);
            o[4] = f2bf(b.x); o[5] = f2bf(b.y); o[6] = f2bf(b.z); o[7] = f2bf(b.w);
            *(u16x8*)&xl[(st0 + 8 * j) * D_MODEL + (sc8 ^ sswz)] = o;
        }
        // issue next-batch prefetch (in flight across all barriers below)
        if (i < 7) {
            const float* xb = x + (size_t)(b0 + i + 1) * (NTOK * D_MODEL);
            #pragma unroll
            for (int j = 0; j < 8; ++j) {
                const float* p = xb + (st0 + 8 * j) * D_MODEL + sc8;
                pre[2 * j]     = *(const float4*)p;
                pre[2 * j + 1] = *(const float4*)(p + 4);
            }
        }
        asm volatile("s_waitcnt lgkmcnt(0)" ::: "memory");
        __builtin_amdgcn_s_barrier();                                    // [1]

        // ---- phase A: S^T[h, n] via MFMA (waves 0-3; wave = 16-token tile) ----
        float ev[4];
        if (w < 4) {
            f32x4 sacc = {0.f, 0.f, 0.f, 0.f};
            const int tok = w * 16 + lr;
            const int rbase = tok * D_MODEL;
            const int rsw = (tok & 7) << 3;
            const int usw = (lr & 7) << 3;
            #pragma unroll
            for (int ks = 0; ks < 16; ++ks) {
                int off = ks * 32 + hg * 8;
                short8 uf;
                if (lr < 8) uf = *(const short8*)&ul[lr * D_MODEL + (off ^ usw)];
                else        uf = (short8){0, 0, 0, 0, 0, 0, 0, 0};
                short8 xf = *(const short8*)&xl[rbase + (off ^ rsw)];
                sacc = __builtin_amdgcn_mfma_f32_16x16x32_bf16(uf, xf, sacc, 0, 0, 0);
            }
            float zsum[4];
            #pragma unroll
            for (int j = 0; j < 4; ++j) {
                float e = __expf(sacc[j]);   // scores O(0.1): no max subtraction
                ev[j] = e;
                e += __shfl_xor(e, 1); e += __shfl_xor(e, 2);
                e += __shfl_xor(e, 4); e += __shfl_xor(e, 8);
                zsum[j] = e;
            }
            if (lr == 0) {
                f32x4 zz = {zsum[0], zsum[1], zsum[2], zsum[3]};
                *(f32x4*)&zred[w][hg * 4] = zz;
            }
        }
        asm volatile("s_waitcnt lgkmcnt(0)" ::: "memory");
        __builtin_amdgcn_s_barrier();                                    // [2]

        // ---- phase B: finish softmax, write attn (f32, normalized) ----
        if (w < 4 && hg < 2) {
            f32x4 z0 = *(const f32x4*)&zred[0][hg * 4];
            f32x4 z1 = *(const f32x4*)&zred[1][hg * 4];
            f32x4 z2 = *(const f32x4*)&zred[2][hg * 4];
            f32x4 z3 = *(const f32x4*)&zred[3][hg * 4];
            int tok = w * 16 + lr;
            f32x4 a;
            #pragma unroll
            for (int j = 0; j < 4; ++j) {
                float zt = z0[j] + z1[j] + z2[j] + z3[j];
                a[j] = ev[j] * __frcp_rn(zt);
            }
            *(f32x4*)&attn_l[tok * 8 + hg * 4] = a;
        }
        asm volatile("s_waitcnt lgkmcnt(0)" ::: "memory");
        __builtin_amdgcn_s_barrier();                                    // [3]

        // ---- phase C accumulate: thread = 8ch x 2heads x 32 tokens ----
        const int oct8 = (tid & 63) * 8;      // channel octet
        const int hp = (tid >> 6) & 3;        // head pair: heads hp*2, hp*2+1
        const int half = tid >> 8;            // token half
        float acc[16];
        #pragma unroll
        for (int k = 0; k < 16; ++k) acc[k] = 0.f;
        {
            const int nb = half * 32;
            #pragma unroll 8
            for (int n = nb; n < nb + 32; ++n) {
                u16x8 xr = *(const u16x8*)&xl[n * D_MODEL + (oct8 ^ ((n & 7) << 3))];
                float2 at = *(const float2*)&attn_l[n * 8 + hp * 2];
                #pragma unroll
                for (int cc = 0; cc < 8; ++cc) {
                    float xf = bf2f(xr[cc]);
                    acc[cc]     += at.x * xf;
                    acc[8 + cc] += at.y * xf;
                }
            }
        }
        asm volatile("s_waitcnt lgkmcnt(0)" ::: "memory");
        __builtin_amdgcn_s_barrier();                                    // [4]

        // ---- cross-half reduce through xl-region scratch ----
        // stride-20 f32 slots (80 B, 16B-aligned; 20 mod 32 spreads quarter-wave
        // lanes at worst 2-way = free).  NO XOR: v7's XOR escaped the slot and
        // collided with the neighbor slot (absmax 2.5 bug).
        float* scr = (float*)xl;              // 256 * 20 * 4 = 20 KB < 64 KB
        const int s = tid & 255;
        if (half) {
            #pragma unroll
            for (int k = 0; k < 4; ++k) {
                f32x4 v = {acc[k * 4], acc[k * 4 + 1], acc[k * 4 + 2], acc[k * 4 + 3]};
                *(f32x4*)&scr[s * 20 + k * 4] = v;
            }
        }
        asm volatile("s_waitcnt lgkmcnt(0)" ::: "memory");
        __builtin_amdgcn_s_barrier();                                    // [5]
        if (!half) {
            #pragma unroll
            for (int k = 0; k < 4; ++k) {
                f32x4 v = *(const f32x4*)&scr[s * 20 + k * 4];
                acc[k * 4] += v[0]; acc[k * 4 + 1] += v[1];
                acc[k * 4 + 2] += v[2]; acc[k * 4 + 3] += v[3];
            }
            unsigned short* pb = pooled + (size_t)(b0 + i) * (N_HEAD * D_MODEL);
            u16x8 o0, o1;
            #pragma unroll
            for (int cc = 0; cc < 8; ++cc) {
                o0[cc] = f2bf(acc[cc]);
                o1[cc] = f2bf(acc[8 + cc]);
            }
            *(u16x8*)&pb[(hp * 2) * D_MODEL + oct8] = o0;
            *(u16x8*)&pb[(hp * 2 + 1) * D_MODEL + oct8] = o1;
        }
        asm volatile("s_waitcnt lgkmcnt(0)" ::: "memory");
        __builtin_amdgcn_s_barrier();                                    // [6]
        // xl (incl. scratch region) now free for next iteration's staging
    }
}

// ---------------------------------------------------------------------------
// MFMA GEMM (unchanged): global_load_lds staging, XOR-swizzled via
// pre-swizzled global source, 4 waves (2x2).  MODE 0: per-head, bf16+bias.
// MODE 1: bf16, gelu(+bias).  MODE 2: f32, +bias +residual(bf16).
// ---------------------------------------------------------------------------
template <int BM, int BN, int MODE>
__global__ __launch_bounds__(256) void gemm_mf(
    const unsigned short* __restrict__ A, int lda,
    const unsigned short* __restrict__ BT,
    const float* __restrict__ bias,
    void* __restrict__ Cout, int ldc,
    const unsigned short* __restrict__ res, int K) {
    __shared__ unsigned short Al[BM * 64];
    __shared__ unsigned short Bl[BN * 64];
    int m0 = blockIdx.x * BM;
    int n0;
    const unsigned short* Ap = A;
    const unsigned short* Bp;
    const float* bp;
    if (MODE == 0) {
        int h = blockIdx.y;
        Ap = A + (size_t)h * 512;
        Bp = BT + (size_t)h * 64 * K;
        bp = bias + h * 64;
        n0 = h * 64;
    } else {
        n0 = blockIdx.y * BN;
        Bp = BT + (size_t)n0 * K;
        bp = bias + n0;
    }
    int tid = threadIdx.x, l = tid & 63, w = tid >> 6;
    int lr = l & 15, lq = l >> 4;
    int wm = w >> 1, wn = w & 1;
    constexpr int MR = BM / 32, NR = BN / 32;
    constexpr int AI = BM / 8, BI = BN / 8;

    f32x4 acc[MR][NR];
    #pragma unroll
    for (int mi = 0; mi < MR; ++mi)
        #pragma unroll
        for (int nj = 0; nj < NR; ++nj) acc[mi][nj] = (f32x4){0.f, 0.f, 0.f, 0.f};

    int srow = l >> 3;
    int scol = ((l & 7) ^ ((l >> 3) & 7)) << 3;

    for (int k0 = 0; k0 < K; k0 += 64) {
        #pragma unroll
        for (int j = 0; j < AI / 4; ++j) {
            int ji = w * (AI / 4) + j;
            const unsigned short* src = Ap + (size_t)(m0 + ji * 8 + srow) * lda + k0 + scol;
            gload_lds16(src, &Al[ji * 512]);
        }
        #pragma unroll
        for (int j = 0; j < BI / 4; ++j) {
            int ji = w * (BI / 4) + j;
            const unsigned short* src = Bp + (size_t)(ji * 8 + srow) * K + k0 + scol;
            gload_lds16(src, &Bl[ji * 512]);
        }
        __syncthreads();
        #pragma unroll
        for (int kk = 0; kk < 64; kk += 32) {
            int sw = (kk + lq * 8) ^ ((l & 7) << 3);
            short8 af[MR], bf[NR];
            #pragma unroll
            for (int mi = 0; mi < MR; ++mi)
                af[mi] = *(const short8*)&Al[(wm * (BM / 2) + mi * 16 + lr) * 64 + sw];
            #pragma unroll
            for (int nj = 0; nj < NR; ++nj)
                bf[nj] = *(const short8*)&Bl[(wn * (BN / 2) + nj * 16 + lr) * 64 + sw];
            #pragma unroll
            for (int mi = 0; mi < MR; ++mi)
                #pragma unroll
                for (int nj = 0; nj < NR; ++nj)
                    acc[mi][nj] = __builtin_amdgcn_mfma_f32_16x16x32_bf16(
                        af[mi], bf[nj], acc[mi][nj], 0, 0, 0);
        }
        __syncthreads();
    }

    #pragma unroll
    for (int mi = 0; mi < MR; ++mi) {
        #pragma unroll
        for (int nj = 0; nj < NR; ++nj) {
            #pragma unroll
            for (int j = 0; j < 4; ++j) {
                int row = m0 + wm * (BM / 2) + mi * 16 + lq * 4 + j;
                int nl = wn * (BN / 2) + nj * 16 + lr;
                int col = n0 + nl;
                float v = acc[mi][nj][j] + bp[nl];
                if (MODE == 1) {
                    v = 0.5f * v * (1.0f + erff(v * 0.70710678118654752f));
                }
                if (MODE == 2) {
                    v += bf2f(res[(size_t)row * 512 + col]);
                    ((float*)Cout)[(size_t)row * ldc + col] = v;
                } else {
                    ((unsigned short*)Cout)[(size_t)row * ldc + col] = f2bf(v);
                }
            }
        }
    }
}

// ---------------------------------------------------------------------------
// K5: in-place LayerNorm over 512, one wave per row
// ---------------------------------------------------------------------------
__global__ __launch_bounds__(256) void ln_kernel(
    float* __restrict__ y, const float* __restrict__ g, const float* __restrict__ bta) {
    int row = blockIdx.x * 4 + (threadIdx.x >> 6);
    int l = threadIdx.x & 63;
    float* yp = y + (size_t)row * D_MODEL;
    float4 v0 = *(const float4*)(yp + l * 8);
    float4 v1 = *(const float4*)(yp + l * 8 + 4);
    float vv[8] = {v0.x, v0.y, v0.z, v0.w, v1.x, v1.y, v1.z, v1.w};
    float s = 0.f;
    #pragma unroll
    for (int i = 0; i < 8; ++i) s += vv[i];
    s = wave_sum(s);
    float mean = s * (1.f / 512.f);
    float q = 0.f;
    #pragma unroll
    for (int i = 0; i < 8; ++i) { float d = vv[i] - mean; q += d * d; }
    q = wave_sum(q);
    float rstd = rsqrtf(q * (1.f / 512.f) + 1e-5f);
    float4 g0 = *(const float4*)(g + l * 8);
    float4 g1 = *(const float4*)(g + l * 8 + 4);
    float4 b0 = *(const float4*)(bta + l * 8);
    float4 b1 = *(const float4*)(bta + l * 8 + 4);
    float gv[8] = {g0.x, g0.y, g0.z, g0.w, g1.x, g1.y, g1.z, g1.w};
    float bv[8] = {b0.x, b0.y, b0.z, b0.w, b1.x, b1.y, b1.z, b1.w};
    float ov[8];
    #pragma unroll
    for (int i = 0; i < 8; ++i) ov[i] = (vv[i] - mean) * rstd * gv[i] + bv[i];
    float4 o0 = {ov[0], ov[1], ov[2], ov[3]};
    float4 o1 = {ov[4], ov[5], ov[6], ov[7]};
    *(float4*)(yp + l * 8) = o0;
    *(float4*)(yp + l * 8 + 4) = o1;
}

extern "C" void kernel_launch(void* const* d_in, const int* in_sizes, int n_in,
                              void* d_out, int out_size, void* d_ws, size_t ws_size,
                              hipStream_t stream) {
    const float* x       = (const float*)d_in[0];
    const float* Wk      = (const float*)d_in[1];
    const float* Wv      = (const float*)d_in[3];
    const float* bv      = (const float*)d_in[4];
    const float* score_w = (const float*)d_in[5];
    const float* W1      = (const float*)d_in[7];
    const float* b1      = (const float*)d_in[8];
    const float* W2      = (const float*)d_in[9];
    const float* b2      = (const float*)d_in[10];
    const float* ln_g    = (const float*)d_in[11];
    const float* ln_b    = (const float*)d_in[12];
    float* out = (float*)d_out;

    char* ws = (char*)d_ws;
    size_t off = 0;
    auto alloc = [&](size_t sz) {
        void* p = ws + off;
        off = (off + sz + 1023) & ~(size_t)1023;
        return p;
    };
    unsigned short* uT  = (unsigned short*)alloc((size_t)16 * D_MODEL * 2);
    unsigned short* WvT = (unsigned short*)alloc((size_t)512 * 512 * 2);
    unsigned short* W1T = (unsigned short*)alloc((size_t)2048 * 512 * 2);
    unsigned short* W2T = (unsigned short*)alloc((size_t)512 * 2048 * 2);
    unsigned short* pooled = (unsigned short*)alloc((size_t)BATCH * N_HEAD * D_MODEL * 2);
    unsigned short* feat   = (unsigned short*)alloc((size_t)BATCH * D_MODEL * 2);
    unsigned short* Hbuf   = (unsigned short*)alloc((size_t)BATCH * D_HIDDEN * 2);

    prep_all<<<dim3(1024, 4), dim3(256), 0, stream>>>(
        Wk, score_w, Wv, W1, W2, uT, WvT, W1T, W2T);
    score_pool_v7<<<dim3(512), dim3(512), 0, stream>>>(x, uT, pooled);
    // proj: feature = pooled @ blockdiag(Wv per head) + bv
    gemm_mf<128, 64, 0><<<dim3(32, 8), dim3(256), 0, stream>>>(
        pooled, N_HEAD * D_MODEL, WvT, bv, (void*)feat, D_MODEL,
        (const unsigned short*)nullptr, 512);
    // ffn1: H = gelu(feature @ W1 + b1)
    gemm_mf<128, 128, 1><<<dim3(32, 16), dim3(256), 0, stream>>>(
        feat, D_MODEL, W1T, b1, (void*)Hbuf, D_HIDDEN,
        (const unsigned short*)nullptr, 512);
    // ffn2: y = H @ W2 + b2 + feature  (f32 -> d_out)
    gemm_mf<64, 128, 2><<<dim3(64, 4), dim3(256), 0, stream>>>(
        Hbuf, D_HIDDEN, W2T, b2, (void*)out, D_MODEL, feat, 2048);
    ln_kernel<<<dim3(1024), dim3(256), 0, stream>>>(out, ln_g, ln_b);
}

// Round 9
// 213.498 us; speedup vs baseline: 5.1030x; 1.3701x over previous
//
#include <hip/hip_runtime.h>
#include <hip/hip_bf16.h>

#define N_HEAD 8
#define D_MODEL 512
#define D_HEAD 64
#define D_HIDDEN 2048
#define NTOK 64
#define BATCH 4096

typedef __attribute__((ext_vector_type(4))) float f32x4;
typedef __attribute__((ext_vector_type(8))) short short8;
typedef __attribute__((ext_vector_type(8))) unsigned short u16x8;

__device__ __forceinline__ float bf2f(unsigned short u) {
    return __uint_as_float(((unsigned int)u) << 16);
}
__device__ __forceinline__ unsigned short f2bf(float f) {
    unsigned int b = __float_as_uint(f);
    b += 0x7fffu + ((b >> 16) & 1u);
    return (unsigned short)(b >> 16);
}
__device__ __forceinline__ float wave_sum(float v) {
    v += __shfl_xor(v, 32); v += __shfl_xor(v, 16); v += __shfl_xor(v, 8);
    v += __shfl_xor(v, 4);  v += __shfl_xor(v, 2);  v += __shfl_xor(v, 1);
    return v;
}
__device__ __forceinline__ void gload_lds16(const void* g, void* l) {
    __builtin_amdgcn_global_load_lds(
        (const __attribute__((address_space(1))) unsigned int*)g,
        (__attribute__((address_space(3))) unsigned int*)l, 16, 0, 0);
}

// ---------------------------------------------------------------------------
// K0: merged prep. y=0..2: transpose {Wv,W1,W2} f32 -> bf16 (N x K);
// y=3: uT[16][512] bf16, uT[h][c] = sum_d Wk[c][h*64+d]*score_w[h][d],
// heads 8..15 zero (per-head consts cancel in softmax; bk/score_b unused).
// ---------------------------------------------------------------------------
__global__ __launch_bounds__(256) void prep_all(
    const float* __restrict__ Wk, const float* __restrict__ score_w,
    const float* __restrict__ Wv, const float* __restrict__ W1,
    const float* __restrict__ W2,
    unsigned short* __restrict__ uT,
    unsigned short* __restrict__ WvT, unsigned short* __restrict__ W1T,
    unsigned short* __restrict__ W2T) {
    int m = blockIdx.y;
    if (m == 3) {
        int idx = blockIdx.x * 256 + threadIdx.x;
        if (idx < 16 * 512) {
            int h = idx & 15, c = idx >> 4;
            float s = 0.f;
            if (h < 8) {
                #pragma unroll 8
                for (int d = 0; d < D_HEAD; ++d)
                    s += Wk[c * D_MODEL + h * D_HEAD + d] * score_w[h * D_HEAD + d];
            }
            uT[h * D_MODEL + c] = f2bf(s);
        }
        return;
    }
    const float* in; unsigned short* out; int K, N, tX, tiles;
    if (m == 0)      { in = Wv; out = WvT; K = 512;  N = 512;  tX = 16; tiles = 256;  }
    else if (m == 1) { in = W1; out = W1T; K = 512;  N = 2048; tX = 64; tiles = 1024; }
    else             { in = W2; out = W2T; K = 2048; N = 512;  tX = 16; tiles = 1024; }
    int t = blockIdx.x;
    if (t >= tiles) return;
    int n0 = (t % tX) * 32, k0 = (t / tX) * 32;
    __shared__ float tile[32][33];
    int tx = threadIdx.x & 31, ty = threadIdx.x >> 5;
    #pragma unroll
    for (int i = ty; i < 32; i += 8)
        tile[i][tx] = in[(size_t)(k0 + i) * N + n0 + tx];
    __syncthreads();
    #pragma unroll
    for (int i = ty; i < 32; i += 8)
        out[(size_t)(n0 + i) * K + k0 + tx] = f2bf(tile[tx][i]);
}

// ---------------------------------------------------------------------------
// K1 v9: quarter-batch pipelining for high occupancy.  1024 blocks x 256 thr
// (4 waves), 4 batches/block, LDS ~25.8 KB -> 5-6 blocks/CU, ALL blocks
// resident (no tail).  Per 16-token quarter: stage (regs->swizzled bf16 LDS,
// 4 x b128/thread) -> barA -> MFMA scores by one rotating wave (+exp -> el,
// Z accumulated in LDS) -> barB -> pool-accumulate by all 4 waves (acc[16]
// f32 in regs across the whole batch; normalize by 1/Z at batch end) -> barC.
// x read ONCE from HBM; next quarter's loads (8 x float4/thread) issued right
// after staging and stay in flight across raw s_barriers (lgkmcnt-only).
// Numerics identical to validated v5/v7 path.
// ---------------------------------------------------------------------------
__global__ __launch_bounds__(256) void score_pool_v9(
    const float* __restrict__ x, const unsigned short* __restrict__ uT,
    unsigned short* __restrict__ pooled) {
    __shared__ unsigned short xl[16 * D_MODEL];   // 16 KB quarter tile
    __shared__ unsigned short ul[8 * D_MODEL];    // 8 KB swizzled uT rows 0..7
    __shared__ float el[16 * 8];                  // 512 B unnormalized e[t][h]
    __shared__ float zacc[8];                     // 32 B running Z per head

    const int tid = threadIdx.x;
    const int l = tid & 63, w = tid >> 6;         // 4 waves
    const int hg = l >> 4, lr = l & 15;

    // ul init: 8 rows x 512 ch, swizzled like xl rows
    {
        int r = tid >> 5;                  // 0..7
        int c16 = (tid & 31) * 16;
        u16x8 v0 = *(const u16x8*)(uT + r * D_MODEL + c16);
        u16x8 v1 = *(const u16x8*)(uT + r * D_MODEL + c16 + 8);
        *(u16x8*)&ul[r * D_MODEL + ((c16) ^ (r << 3))] = v0;
        *(u16x8*)&ul[r * D_MODEL + ((c16 + 8) ^ (r << 3))] = v1;
    }

    // staging geometry: thread = tile-row r (0..15) x 32 consecutive channels
    const int sr = tid >> 4;               // 0..15
    const int cb = (tid & 15) * 32;        // channel base
    const int ssw = (sr & 7) << 3;

    // pool geometry: thread = channel octet o x head pair hp
    const int o8 = (tid & 63) * 8;
    const int hp = tid >> 6;

    const int b0 = blockIdx.x * 4;

    float4 pre[8];
    {   // prologue: quarter 0 of batch b0
        const float* p = x + (size_t)b0 * (NTOK * D_MODEL) + sr * D_MODEL + cb;
        #pragma unroll
        for (int j = 0; j < 8; ++j) pre[j] = *(const float4*)(p + j * 4);
    }

    float acc[16];
    #pragma unroll
    for (int k = 0; k < 16; ++k) acc[k] = 0.f;

    #pragma unroll 1
    for (int qq = 0; qq < 16; ++qq) {
        const int q = qq & 3;
        // ---- stage: regs -> swizzled bf16 LDS ----
        if (q == 0 && tid < 8) zacc[tid] = 0.f;   // ordered before use by barA
        #pragma unroll
        for (int j2 = 0; j2 < 4; ++j2) {
            float4 a = pre[2 * j2], b = pre[2 * j2 + 1];
            u16x8 ov;
            ov[0] = f2bf(a.x); ov[1] = f2bf(a.y); ov[2] = f2bf(a.z); ov[3] = f2bf(a.w);
            ov[4] = f2bf(b.x); ov[5] = f2bf(b.y); ov[6] = f2bf(b.z); ov[7] = f2bf(b.w);
            *(u16x8*)&xl[sr * D_MODEL + ((cb + j2 * 8) ^ ssw)] = ov;
        }
        // issue next quarter's loads (stay in flight across all barriers)
        if (qq < 15) {
            const int nb = b0 + ((qq + 1) >> 2), nq = (qq + 1) & 3;
            const float* p = x + (size_t)nb * (NTOK * D_MODEL) +
                             (nq * 16 + sr) * D_MODEL + cb;
            #pragma unroll
            for (int j = 0; j < 8; ++j) pre[j] = *(const float4*)(p + j * 4);
        }
        asm volatile("s_waitcnt lgkmcnt(0)" ::: "memory");
        __builtin_amdgcn_s_barrier();                                    // A

        // ---- score: one rotating wave does 16 MFMAs + exp + Z ----
        if (w == q) {
            f32x4 sacc = {0.f, 0.f, 0.f, 0.f};
            const int rbase = lr * D_MODEL;
            const int rsw = (lr & 7) << 3;
            #pragma unroll
            for (int ks = 0; ks < 16; ++ks) {
                int off = ks * 32 + hg * 8;
                short8 uf;
                if (lr < 8) uf = *(const short8*)&ul[lr * D_MODEL + (off ^ (lr << 3))];
                else        uf = (short8){0, 0, 0, 0, 0, 0, 0, 0};
                short8 xf = *(const short8*)&xl[rbase + (off ^ rsw)];
                sacc = __builtin_amdgcn_mfma_f32_16x16x32_bf16(uf, xf, sacc, 0, 0, 0);
            }
            f32x4 ev;
            float zsum[4];
            #pragma unroll
            for (int j = 0; j < 4; ++j) {
                float e = __expf(sacc[j]);   // scores O(0.1): no max subtraction
                ev[j] = e;
                e += __shfl_xor(e, 1); e += __shfl_xor(e, 2);
                e += __shfl_xor(e, 4); e += __shfl_xor(e, 8);
                zsum[j] = e;
            }
            if (hg < 2) {
                *(f32x4*)&el[lr * 8 + hg * 4] = ev;
                if (lr == 0) {
                    f32x4 z = *(const f32x4*)&zacc[hg * 4];
                    z[0] += zsum[0]; z[1] += zsum[1];
                    z[2] += zsum[2]; z[3] += zsum[3];
                    *(f32x4*)&zacc[hg * 4] = z;
                }
            }
        }
        asm volatile("s_waitcnt lgkmcnt(0)" ::: "memory");
        __builtin_amdgcn_s_barrier();                                    // B

        // ---- pool accumulate: all 4 waves, 16 tokens ----
        #pragma unroll 4
        for (int t = 0; t < 16; ++t) {
            u16x8 xr = *(const u16x8*)&xl[t * D_MODEL + (o8 ^ ((t & 7) << 3))];
            float2 e2 = *(const float2*)&el[t * 8 + hp * 2];
            #pragma unroll
            for (int cc = 0; cc < 8; ++cc) {
                float xf = bf2f(xr[cc]);
                acc[cc]     += e2.x * xf;
                acc[8 + cc] += e2.y * xf;
            }
        }
        // ---- batch end: normalize and write ----
        if (q == 3) {
            float2 za = *(const float2*)&zacc[hp * 2];
            float r0 = 1.f / za.x, r1 = 1.f / za.y;
            unsigned short* pb = pooled + (size_t)(b0 + (qq >> 2)) * (N_HEAD * D_MODEL);
            u16x8 o0, o1;
            #pragma unroll
            for (int cc = 0; cc < 8; ++cc) {
                o0[cc] = f2bf(acc[cc] * r0);
                o1[cc] = f2bf(acc[8 + cc] * r1);
            }
            *(u16x8*)&pb[(hp * 2) * D_MODEL + o8] = o0;
            *(u16x8*)&pb[(hp * 2 + 1) * D_MODEL + o8] = o1;
            #pragma unroll
            for (int k = 0; k < 16; ++k) acc[k] = 0.f;
        }
        asm volatile("s_waitcnt lgkmcnt(0)" ::: "memory");
        __builtin_amdgcn_s_barrier();                                    // C
        // xl/el/zacc free for next quarter's stage
    }
}

// ---------------------------------------------------------------------------
// MFMA GEMM (unchanged): global_load_lds staging, XOR-swizzled via
// pre-swizzled global source, 4 waves (2x2).  MODE 0: per-head, bf16+bias.
// MODE 1: bf16, gelu(+bias).  MODE 2: f32, +bias +residual(bf16).
// ---------------------------------------------------------------------------
template <int BM, int BN, int MODE>
__global__ __launch_bounds__(256) void gemm_mf(
    const unsigned short* __restrict__ A, int lda,
    const unsigned short* __restrict__ BT,
    const float* __restrict__ bias,
    void* __restrict__ Cout, int ldc,
    const unsigned short* __restrict__ res, int K) {
    __shared__ unsigned short Al[BM * 64];
    __shared__ unsigned short Bl[BN * 64];
    int m0 = blockIdx.x * BM;
    int n0;
    const unsigned short* Ap = A;
    const unsigned short* Bp;
    const float* bp;
    if (MODE == 0) {
        int h = blockIdx.y;
        Ap = A + (size_t)h * 512;
        Bp = BT + (size_t)h * 64 * K;
        bp = bias + h * 64;
        n0 = h * 64;
    } else {
        n0 = blockIdx.y * BN;
        Bp = BT + (size_t)n0 * K;
        bp = bias + n0;
    }
    int tid = threadIdx.x, l = tid & 63, w = tid >> 6;
    int lr = l & 15, lq = l >> 4;
    int wm = w >> 1, wn = w & 1;
    constexpr int MR = BM / 32, NR = BN / 32;
    constexpr int AI = BM / 8, BI = BN / 8;

    f32x4 acc[MR][NR];
    #pragma unroll
    for (int mi = 0; mi < MR; ++mi)
        #pragma unroll
        for (int nj = 0; nj < NR; ++nj) acc[mi][nj] = (f32x4){0.f, 0.f, 0.f, 0.f};

    int srow = l >> 3;
    int scol = ((l & 7) ^ ((l >> 3) & 7)) << 3;

    for (int k0 = 0; k0 < K; k0 += 64) {
        #pragma unroll
        for (int j = 0; j < AI / 4; ++j) {
            int ji = w * (AI / 4) + j;
            const unsigned short* src = Ap + (size_t)(m0 + ji * 8 + srow) * lda + k0 + scol;
            gload_lds16(src, &Al[ji * 512]);
        }
        #pragma unroll
        for (int j = 0; j < BI / 4; ++j) {
            int ji = w * (BI / 4) + j;
            const unsigned short* src = Bp + (size_t)(ji * 8 + srow) * K + k0 + scol;
            gload_lds16(src, &Bl[ji * 512]);
        }
        __syncthreads();
        #pragma unroll
        for (int kk = 0; kk < 64; kk += 32) {
            int sw = (kk + lq * 8) ^ ((l & 7) << 3);
            short8 af[MR], bf[NR];
            #pragma unroll
            for (int mi = 0; mi < MR; ++mi)
                af[mi] = *(const short8*)&Al[(wm * (BM / 2) + mi * 16 + lr) * 64 + sw];
            #pragma unroll
            for (int nj = 0; nj < NR; ++nj)
                bf[nj] = *(const short8*)&Bl[(wn * (BN / 2) + nj * 16 + lr) * 64 + sw];
            #pragma unroll
            for (int mi = 0; mi < MR; ++mi)
                #pragma unroll
                for (int nj = 0; nj < NR; ++nj)
                    acc[mi][nj] = __builtin_amdgcn_mfma_f32_16x16x32_bf16(
                        af[mi], bf[nj], acc[mi][nj], 0, 0, 0);
        }
        __syncthreads();
    }

    #pragma unroll
    for (int mi = 0; mi < MR; ++mi) {
        #pragma unroll
        for (int nj = 0; nj < NR; ++nj) {
            #pragma unroll
            for (int j = 0; j < 4; ++j) {
                int row = m0 + wm * (BM / 2) + mi * 16 + lq * 4 + j;
                int nl = wn * (BN / 2) + nj * 16 + lr;
                int col = n0 + nl;
                float v = acc[mi][nj][j] + bp[nl];
                if (MODE == 1) {
                    v = 0.5f * v * (1.0f + erff(v * 0.70710678118654752f));
                }
                if (MODE == 2) {
                    v += bf2f(res[(size_t)row * 512 + col]);
                    ((float*)Cout)[(size_t)row * ldc + col] = v;
                } else {
                    ((unsigned short*)Cout)[(size_t)row * ldc + col] = f2bf(v);
                }
            }
        }
    }
}

// ---------------------------------------------------------------------------
// K5: in-place LayerNorm over 512, one wave per row
// ---------------------------------------------------------------------------
__global__ __launch_bounds__(256) void ln_kernel(
    float* __restrict__ y, const float* __restrict__ g, const float* __restrict__ bta) {
    int row = blockIdx.x * 4 + (threadIdx.x >> 6);
    int l = threadIdx.x & 63;
    float* yp = y + (size_t)row * D_MODEL;
    float4 v0 = *(const float4*)(yp + l * 8);
    float4 v1 = *(const float4*)(yp + l * 8 + 4);
    float vv[8] = {v0.x, v0.y, v0.z, v0.w, v1.x, v1.y, v1.z, v1.w};
    float s = 0.f;
    #pragma unroll
    for (int i = 0; i < 8; ++i) s += vv[i];
    s = wave_sum(s);
    float mean = s * (1.f / 512.f);
    float q = 0.f;
    #pragma unroll
    for (int i = 0; i < 8; ++i) { float d = vv[i] - mean; q += d * d; }
    q = wave_sum(q);
    float rstd = rsqrtf(q * (1.f / 512.f) + 1e-5f);
    float4 g0 = *(const float4*)(g + l * 8);
    float4 g1 = *(const float4*)(g + l * 8 + 4);
    float4 b0 = *(const float4*)(bta + l * 8);
    float4 b1 = *(const float4*)(bta + l * 8 + 4);
    float gv[8] = {g0.x, g0.y, g0.z, g0.w, g1.x, g1.y, g1.z, g1.w};
    float bv[8] = {b0.x, b0.y, b0.z, b0.w, b1.x, b1.y, b1.z, b1.w};
    float ov[8];
    #pragma unroll
    for (int i = 0; i < 8; ++i) ov[i] = (vv[i] - mean) * rstd * gv[i] + bv[i];
    float4 o0 = {ov[0], ov[1], ov[2], ov[3]};
    float4 o1 = {ov[4], ov[5], ov[6], ov[7]};
    *(float4*)(yp + l * 8) = o0;
    *(float4*)(yp + l * 8 + 4) = o1;
}

extern "C" void kernel_launch(void* const* d_in, const int* in_sizes, int n_in,
                              void* d_out, int out_size, void* d_ws, size_t ws_size,
                              hipStream_t stream) {
    const float* x       = (const float*)d_in[0];
    const float* Wk      = (const float*)d_in[1];
    const float* Wv      = (const float*)d_in[3];
    const float* bv      = (const float*)d_in[4];
    const float* score_w = (const float*)d_in[5];
    const float* W1      = (const float*)d_in[7];
    const float* b1      = (const float*)d_in[8];
    const float* W2      = (const float*)d_in[9];
    const float* b2      = (const float*)d_in[10];
    const float* ln_g    = (const float*)d_in[11];
    const float* ln_b    = (const float*)d_in[12];
    float* out = (float*)d_out;

    char* ws = (char*)d_ws;
    size_t off = 0;
    auto alloc = [&](size_t sz) {
        void* p = ws + off;
        off = (off + sz + 1023) & ~(size_t)1023;
        return p;
    };
    unsigned short* uT  = (unsigned short*)alloc((size_t)16 * D_MODEL * 2);
    unsigned short* WvT = (unsigned short*)alloc((size_t)512 * 512 * 2);
    unsigned short* W1T = (unsigned short*)alloc((size_t)2048 * 512 * 2);
    unsigned short* W2T = (unsigned short*)alloc((size_t)512 * 2048 * 2);
    unsigned short* pooled = (unsigned short*)alloc((size_t)BATCH * N_HEAD * D_MODEL * 2);
    unsigned short* feat   = (unsigned short*)alloc((size_t)BATCH * D_MODEL * 2);
    unsigned short* Hbuf   = (unsigned short*)alloc((size_t)BATCH * D_HIDDEN * 2);

    prep_all<<<dim3(1024, 4), dim3(256), 0, stream>>>(
        Wk, score_w, Wv, W1, W2, uT, WvT, W1T, W2T);
    score_pool_v9<<<dim3(1024), dim3(256), 0, stream>>>(x, uT, pooled);
    // proj: feature = pooled @ blockdiag(Wv per head) + bv
    gemm_mf<128, 64, 0><<<dim3(32, 8), dim3(256), 0, stream>>>(
        pooled, N_HEAD * D_MODEL, WvT, bv, (void*)feat, D_MODEL,
        (const unsigned short*)nullptr, 512);
    // ffn1: H = gelu(feature @ W1 + b1)
    gemm_mf<128, 128, 1><<<dim3(32, 16), dim3(256), 0, stream>>>(
        feat, D_MODEL, W1T, b1, (void*)Hbuf, D_HIDDEN,
        (const unsigned short*)nullptr, 512);
    // ffn2: y = H @ W2 + b2 + feature  (f32 -> d_out)
    gemm_mf<64, 128, 2><<<dim3(64, 4), dim3(256), 0, stream>>>(
        Hbuf, D_HIDDEN, W2T, b2, (void*)out, D_MODEL, feat, 2048);
    ln_kernel<<<dim3(1024), dim3(256), 0, stream>>>(out, ln_g, ln_b);
}